// Round 1
// baseline (125.118 us; speedup 1.0000x reference)
//
#include <hip/hip_runtime.h>

#define TPB 256
#define PTS 4          // query points per thread
#define CHUNK 512      // database points staged per block

// ws[0..B*N) = dist1 bits, ws[B*N..B*N+B*M) = dist2 bits
__global__ void init_inf(unsigned* __restrict__ w, int n) {
    int i = blockIdx.x * blockDim.x + threadIdx.x;
    if (i < n) w[i] = 0x7F800000u;   // +inf
}

__global__ __launch_bounds__(TPB, 4) void nn_min(
        const float* __restrict__ pos, const float* __restrict__ xhat,
        unsigned* __restrict__ d1bits, unsigned* __restrict__ d2bits,
        int N, int M) {
    const int bz  = blockIdx.z;       // b*2 + dir
    const int b   = bz >> 1;
    const int dir = bz & 1;
    // dir 0: queries = pos (N), database = xhat (M) -> dist1
    // dir 1: queries = xhat (M), database = pos (N) -> dist2
    const float* A  = dir ? xhat : pos;
    const float* Bp = dir ? pos  : xhat;
    const int NA = dir ? M : N;
    const int NB = dir ? N : M;
    unsigned* outb = (dir ? d2bits : d1bits) + (size_t)b * NA;

    __shared__ float4 sB[CHUNK * 3 / 4];   // 6 KB

    // ---- stage database chunk (coalesced float4) ----
    const int mbase = blockIdx.y * CHUNK;
    const int mlen  = min(CHUNK, NB - mbase);          // 512 for our sizes
    const float4* gB = (const float4*)(Bp + (size_t)(b * NB + mbase) * 3);
    const int nvec = mlen * 3 / 4;
    for (int j = threadIdx.x; j < nvec; j += TPB) sB[j] = gB[j];

    // ---- load query points into registers ----
    const int i0 = blockIdx.x * (TPB * PTS) + threadIdx.x;
    float ax[PTS], ay[PTS], az[PTS], mn[PTS];
#pragma unroll
    for (int k = 0; k < PTS; k++) {
        int i = i0 + k * TPB;
        int ic = i < NA ? i : NA - 1;                  // clamp (no OOB read)
        const float* p = A + (size_t)(b * NA + ic) * 3;
        ax[k] = p[0]; ay[k] = p[1]; az[k] = p[2];
        mn[k] = 3.4e38f;
    }
    __syncthreads();

    // ---- min over chunk: 4 db points per step via 3 broadcast b128 reads ----
    for (int j = 0; j < mlen; j += 4) {
        const int q = (j >> 2) * 3;
        float4 q0 = sB[q + 0];
        float4 q1 = sB[q + 1];
        float4 q2 = sB[q + 2];
        float bx[4] = {q0.x, q0.w, q1.z, q2.y};
        float by[4] = {q0.y, q1.x, q1.w, q2.z};
        float bz_[4] = {q0.z, q1.y, q2.x, q2.w};
#pragma unroll
        for (int t = 0; t < 4; t++) {
#pragma unroll
            for (int k = 0; k < PTS; k++) {
                float dx = ax[k] - bx[t];
                float dy = ay[k] - by[t];
                float dz = az[k] - bz_[t];
                float d  = fmaf(dz, dz, fmaf(dy, dy, dx * dx));
                mn[k] = fminf(mn[k], d);
            }
        }
    }

    // ---- combine partial mins across m-chunks ----
#pragma unroll
    for (int k = 0; k < PTS; k++) {
        int i = i0 + k * TPB;
        if (i < NA) atomicMin(&outb[i], __float_as_uint(mn[k]));
    }
}

__global__ void reduce_loss(const unsigned* __restrict__ d1,
                            const unsigned* __restrict__ d2,
                            int n1, int n2, float* __restrict__ out) {
    __shared__ double sh[TPB];
    double s = 0.0;
    for (int i = threadIdx.x; i < n1; i += TPB)
        s += (double)__uint_as_float(d1[i]) / (double)n1;
    for (int i = threadIdx.x; i < n2; i += TPB)
        s += (double)__uint_as_float(d2[i]) / (double)n2;
    sh[threadIdx.x] = s;
    __syncthreads();
    for (int off = TPB / 2; off > 0; off >>= 1) {
        if (threadIdx.x < off) sh[threadIdx.x] += sh[threadIdx.x + off];
        __syncthreads();
    }
    if (threadIdx.x == 0) {
        float L = (float)sh[0];
        out[0] = L;   // loss
        out[1] = L;   // rec_loss
    }
}

extern "C" void kernel_launch(void* const* d_in, const int* in_sizes, int n_in,
                              void* d_out, int out_size, void* d_ws, size_t ws_size,
                              hipStream_t stream) {
    const float* pos  = (const float*)d_in[0];
    const float* xhat = (const float*)d_in[1];
    const int B = 2;
    const int N = in_sizes[0] / (B * 3);   // 8192
    const int M = in_sizes[1] / (B * 3);   // 8192

    unsigned* d1 = (unsigned*)d_ws;
    unsigned* d2 = d1 + (size_t)B * N;
    const int tot = B * (N + M);

    init_inf<<<(tot + 255) / 256, 256, 0, stream>>>(d1, tot);

    // N == M for this problem; grid covers both directions
    dim3 grid((N + TPB * PTS - 1) / (TPB * PTS),   // 8 query tiles
              (M + CHUNK - 1) / CHUNK,             // 16 db chunks
              B * 2);                              // batch x direction
    nn_min<<<grid, TPB, 0, stream>>>(pos, xhat, d1, d2, N, M);

    reduce_loss<<<1, TPB, 0, stream>>>(d1, d2, B * N, B * M, (float*)d_out);
}

// Round 2
// 87.399 us; speedup vs baseline: 1.4316x; 1.4316x over previous
//
#include <hip/hip_runtime.h>

#define TPB 256
#define PTS 4          // query points per thread
#define CHUNK 512      // database points staged per block

// ws[0..B*N) = dist1 bits, ws[B*N..B*N+B*M) = dist2 bits (uint-ordered fp32, all >= 0)

__global__ void init_inf(unsigned* __restrict__ w, int n, float* __restrict__ out) {
    int i = blockIdx.x * blockDim.x + threadIdx.x;
    if (i < n) w[i] = 0x7F800000u;   // +inf
    if (i == 0) { out[0] = 0.0f; out[1] = 0.0f; }
}

__global__ __launch_bounds__(TPB, 4) void nn_min(
        const float* __restrict__ pos, const float* __restrict__ xhat,
        unsigned* __restrict__ d1bits, unsigned* __restrict__ d2bits,
        int N, int M) {
    const int bz  = blockIdx.z;       // b*2 + dir
    const int b   = bz >> 1;
    const int dir = bz & 1;
    // dir 0: queries = pos (N), database = xhat (M) -> dist1
    // dir 1: queries = xhat (M), database = pos (N) -> dist2
    const float* A  = dir ? xhat : pos;
    const float* Bp = dir ? pos  : xhat;
    const int NA = dir ? M : N;
    const int NB = dir ? N : M;
    unsigned* outb = (dir ? d2bits : d1bits) + (size_t)b * NA;

    const int mbase = blockIdx.y * CHUNK;
    if (mbase >= NB) return;                     // block-uniform early exit
    const int mlen = min(CHUNK, NB - mbase);

    // ---- stage database chunk with precomputed (-2bx,-2by,-2bz, |b|^2) ----
    __shared__ float4 sB[CHUNK];                 // 8 KB
    for (int j = threadIdx.x; j < mlen; j += TPB) {
        const float* p = Bp + (size_t)(b * NB + mbase + j) * 3;
        float x = p[0], y = p[1], z = p[2];
        sB[j] = make_float4(-2.0f * x, -2.0f * y, -2.0f * z,
                            x * x + y * y + z * z);
    }

    // ---- load query points into registers ----
    const int i0 = blockIdx.x * (TPB * PTS) + threadIdx.x;
    float ax[PTS], ay[PTS], az[PTS], ca[PTS], mn[PTS];
#pragma unroll
    for (int k = 0; k < PTS; k++) {
        int i = i0 + k * TPB;
        int ic = i < NA ? i : NA - 1;            // clamp (no OOB read)
        const float* p = A + (size_t)(b * NA + ic) * 3;
        ax[k] = p[0]; ay[k] = p[1]; az[k] = p[2];
        ca[k] = ax[k] * ax[k] + ay[k] * ay[k] + az[k] * az[k];
        mn[k] = 3.4e38f;
    }
    __syncthreads();

    // ---- core: per db point 1 broadcast ds_read_b128 + PTS*(3 fma + 1 min) ----
#pragma unroll 4
    for (int j = 0; j < mlen; ++j) {
        float4 q = sB[j];
#pragma unroll
        for (int k = 0; k < PTS; k++) {
            float s = fmaf(ax[k], q.x,
                      fmaf(ay[k], q.y,
                      fmaf(az[k], q.z, q.w)));   // |b|^2 - 2 a.b
            mn[k] = fminf(mn[k], s);
        }
    }

    // ---- combine partial mins across m-chunks ----
#pragma unroll
    for (int k = 0; k < PTS; k++) {
        int i = i0 + k * TPB;
        float d = fmaxf(ca[k] + mn[k], 0.0f);    // exact-ish squared distance, >= 0
        if (i < NA) atomicMin(&outb[i], __float_as_uint(d));
    }
}

__global__ void reduce_loss(const unsigned* __restrict__ d1,
                            const unsigned* __restrict__ d2,
                            int n1, int n2, float inv1, float inv2,
                            float* __restrict__ out) {
    __shared__ float sh[TPB];
    const int stride = gridDim.x * blockDim.x;
    float s = 0.0f;
    for (int i = blockIdx.x * blockDim.x + threadIdx.x; i < n1 + n2; i += stride) {
        s += (i < n1) ? __uint_as_float(d1[i]) * inv1
                      : __uint_as_float(d2[i - n1]) * inv2;
    }
    sh[threadIdx.x] = s;
    __syncthreads();
    for (int off = TPB / 2; off > 0; off >>= 1) {
        if (threadIdx.x < off) sh[threadIdx.x] += sh[threadIdx.x + off];
        __syncthreads();
    }
    if (threadIdx.x == 0) {
        atomicAdd(&out[0], sh[0]);   // loss
        atomicAdd(&out[1], sh[0]);   // rec_loss (identical)
    }
}

extern "C" void kernel_launch(void* const* d_in, const int* in_sizes, int n_in,
                              void* d_out, int out_size, void* d_ws, size_t ws_size,
                              hipStream_t stream) {
    const float* pos  = (const float*)d_in[0];
    const float* xhat = (const float*)d_in[1];
    const int B = 2;
    const int N = in_sizes[0] / (B * 3);   // 8192
    const int M = in_sizes[1] / (B * 3);   // 8192
    float* out = (float*)d_out;

    unsigned* d1 = (unsigned*)d_ws;
    unsigned* d2 = d1 + (size_t)B * N;
    const int tot = B * (N + M);

    init_inf<<<(tot + 255) / 256, 256, 0, stream>>>(d1, tot, out);

    const int mx = N > M ? N : M;
    dim3 grid((mx + TPB * PTS - 1) / (TPB * PTS),   // 8 query tiles
              (mx + CHUNK - 1) / CHUNK,             // 16 db chunks
              B * 2);                               // batch x direction
    nn_min<<<grid, TPB, 0, stream>>>(pos, xhat, d1, d2, N, M);

    reduce_loss<<<128, TPB, 0, stream>>>(d1, d2, B * N, B * M,
                                         1.0f / (B * N), 1.0f / (B * M), out);
}

// Round 3
// 87.341 us; speedup vs baseline: 1.4325x; 1.0007x over previous
//
#include <hip/hip_runtime.h>

#define TPB 256
#define PTS 4          // query points per thread (2 x float2)
#define CHUNK 512      // database points staged per block

typedef float f2 __attribute__((ext_vector_type(2)));

// ws layout: part[bz][group][mx] floats, bz = b*2+dir  (2 MB for B=2, G=16, mx=8192)

__global__ __launch_bounds__(TPB, 4) void nn_min(
        const float* __restrict__ pos, const float* __restrict__ xhat,
        float* __restrict__ part, int N, int M, int mx,
        float* __restrict__ out) {
    // zero the output accumulators (stream-ordered before reduce_loss)
    if (blockIdx.x == 0 && blockIdx.y == 0 && blockIdx.z == 0 && threadIdx.x == 0) {
        out[0] = 0.0f; out[1] = 0.0f;
    }
    const int bz  = blockIdx.z;
    const int b   = bz >> 1;
    const int dir = bz & 1;
    // dir 0: queries = pos (N), database = xhat (M) -> dist1
    // dir 1: queries = xhat (M), database = pos (N) -> dist2
    const float* A  = dir ? xhat : pos;
    const float* Bp = dir ? pos  : xhat;
    const int NA = dir ? M : N;
    const int NB = dir ? N : M;
    const int G  = gridDim.y;
    float* outp = part + (size_t)(bz * G + blockIdx.y) * mx;

    // ---- stage database chunk with precomputed (-2bx,-2by,-2bz, |b|^2) ----
    __shared__ float4 sB[CHUNK];                 // 8 KB
    const int mbase = blockIdx.y * CHUNK;
    const int mlen  = min(CHUNK, NB - mbase);    // 512 for our sizes
    for (int j = threadIdx.x; j < mlen; j += TPB) {
        const float* p = Bp + (size_t)(b * NB + mbase + j) * 3;
        float x = p[0], y = p[1], z = p[2];
        sB[j] = make_float4(-2.0f * x, -2.0f * y, -2.0f * z,
                            x * x + y * y + z * z);
    }

    // ---- load query points into register float2 pairs ----
    const int i0 = blockIdx.x * (TPB * PTS) + threadIdx.x;
    f2 axv[2], ayv[2], azv[2], cav[2], mnv[2];
#pragma unroll
    for (int h = 0; h < 2; h++) {
#pragma unroll
        for (int u = 0; u < 2; u++) {
            int i  = i0 + (h * 2 + u) * TPB;
            int ic = i < NA ? i : NA - 1;        // clamp (no OOB read)
            const float* p = A + (size_t)(b * NA + ic) * 3;
            float x = p[0], y = p[1], z = p[2];
            axv[h][u] = x; ayv[h][u] = y; azv[h][u] = z;
            cav[h][u] = x * x + y * y + z * z;
            mnv[h][u] = 3.4e38f;
        }
    }
    __syncthreads();

    // ---- core: 2 db points/iter, pk-fma chains + v_min3 fold ----
    int j = 0;
#pragma unroll 2
    for (; j + 2 <= mlen; j += 2) {
        float4 q0 = sB[j];
        float4 q1 = sB[j + 1];
#pragma unroll
        for (int h = 0; h < 2; h++) {
            f2 s0 = azv[h] * q0.z + q0.w;        // |b|^2 - 2 a.b (expanded)
            s0    = ayv[h] * q0.y + s0;
            s0    = axv[h] * q0.x + s0;
            f2 s1 = azv[h] * q1.z + q1.w;
            s1    = ayv[h] * q1.y + s1;
            s1    = axv[h] * q1.x + s1;
            mnv[h][0] = fminf(fminf(mnv[h][0], s0[0]), s1[0]);   // -> v_min3_f32
            mnv[h][1] = fminf(fminf(mnv[h][1], s0[1]), s1[1]);
        }
    }
    for (; j < mlen; ++j) {                      // odd tail (not hit at 512)
        float4 q = sB[j];
#pragma unroll
        for (int h = 0; h < 2; h++) {
            f2 s = azv[h] * q.z + q.w;
            s    = ayv[h] * q.y + s;
            s    = axv[h] * q.x + s;
            mnv[h][0] = fminf(mnv[h][0], s[0]);
            mnv[h][1] = fminf(mnv[h][1], s[1]);
        }
    }

    // ---- store partial min per (query, group): plain coalesced store ----
#pragma unroll
    for (int h = 0; h < 2; h++)
#pragma unroll
        for (int u = 0; u < 2; u++) {
            int i = i0 + (h * 2 + u) * TPB;
            if (i < NA)
                outp[i] = fmaxf(cav[h][u] + mnv[h][u], 0.0f);
        }
}

__global__ void reduce_loss(const float* __restrict__ part,
                            int N, int M, int mx, int G, int nbz,
                            float inv1, float inv2, float* __restrict__ out) {
    const int total  = nbz * mx;
    const int stride = gridDim.x * blockDim.x;
    float s = 0.0f;
    for (int t = blockIdx.x * blockDim.x + threadIdx.x; t < total; t += stride) {
        int bz = t / mx;
        int i  = t - bz * mx;
        int dir = bz & 1;
        int NA  = dir ? M : N;
        if (i < NA) {
            const float* p = part + (size_t)(bz * G) * mx + i;
            float mn = p[0];
            for (int g = 1; g < G; ++g)
                mn = fminf(mn, p[(size_t)g * mx]);
            s += mn * (dir ? inv2 : inv1);
        }
    }
    __shared__ float sh[TPB];
    sh[threadIdx.x] = s;
    __syncthreads();
    for (int off = TPB / 2; off > 0; off >>= 1) {
        if (threadIdx.x < off) sh[threadIdx.x] += sh[threadIdx.x + off];
        __syncthreads();
    }
    if (threadIdx.x == 0) {
        atomicAdd(&out[0], sh[0]);   // loss
        atomicAdd(&out[1], sh[0]);   // rec_loss (identical)
    }
}

extern "C" void kernel_launch(void* const* d_in, const int* in_sizes, int n_in,
                              void* d_out, int out_size, void* d_ws, size_t ws_size,
                              hipStream_t stream) {
    const float* pos  = (const float*)d_in[0];
    const float* xhat = (const float*)d_in[1];
    const int B = 2;
    const int N = in_sizes[0] / (B * 3);   // 8192
    const int M = in_sizes[1] / (B * 3);   // 8192
    float* out  = (float*)d_out;
    float* part = (float*)d_ws;

    const int mx    = N > M ? N : M;
    const int tiles = (mx + TPB * PTS - 1) / (TPB * PTS);  // 8
    const int G     = (mx + CHUNK - 1) / CHUNK;            // 16

    dim3 grid(tiles, G, B * 2);                            // 512 blocks
    nn_min<<<grid, TPB, 0, stream>>>(pos, xhat, part, N, M, mx, out);

    reduce_loss<<<128, TPB, 0, stream>>>(part, N, M, mx, G, B * 2,
                                         1.0f / (B * N), 1.0f / (B * M), out);
}